// Round 11
// baseline (36.628 us; speedup 1.0000x reference)
//
#include <hip/hip_runtime.h>
#include <math.h>

// V=4 views, N=8192 points, 6 directed chamfer terms (pair p rows=view pi, min over view pj)
#define VNUM   4
#define NPAIRS 6
#define BLK    256
#define QTILE  1024   // b-points per block == one LDS chunk (32 KB)
#define CHUNK  1024

using short8  = __attribute__((ext_vector_type(8)))  short;
using f32x16  = __attribute__((ext_vector_type(16))) float;

__device__ inline unsigned short f2bf(float x) {           // RNE to bf16
    unsigned u = __float_as_uint(x);
    return (unsigned short)((u + 0x7FFFu + ((u >> 16) & 1u)) >> 16);
}
__device__ inline float bf2f(unsigned short b) {
    return __uint_as_float(((unsigned)b) << 16);
}

// Kernel 1: world-transform, build K=16 bf16 fragments so that
// dot(Afrag[a], Bfrag[b]) = |a|^2 + |b|^2 - 2*(a_hi+a_lo).(b_hi+b_lo).
__global__ void setup_kernel(const float* __restrict__ pts,
                             const float* __restrict__ poses,
                             unsigned short* __restrict__ afr,
                             unsigned short* __restrict__ bfr,
                             unsigned int* __restrict__ minbuf,
                             float* __restrict__ out, int N) {
    int idx = blockIdx.x * blockDim.x + threadIdx.x;
    if (idx < NPAIRS * N) minbuf[idx] = 0x7F7FFFFFu;       // FLT_MAX bits
    if (idx == 0) *out = 0.0f;
    if (idx < VNUM * N) {
        int v = idx / N;
        const float* P = poses + v * 16;                   // row-major 4x4
        float px = pts[idx*3+0], py = pts[idx*3+1], pz = pts[idx*3+2];
        float x = fmaf(P[0], px, fmaf(P[1], py, fmaf(P[2],  pz, P[3])));
        float y = fmaf(P[4], px, fmaf(P[5], py, fmaf(P[6],  pz, P[7])));
        float z = fmaf(P[8], px, fmaf(P[9], py, fmaf(P[10], pz, P[11])));
        float s = fmaf(x, x, fmaf(y, y, z * z));
        unsigned short xh = f2bf(x), yh = f2bf(y), zh = f2bf(z);
        unsigned short xl = f2bf(x - bf2f(xh));
        unsigned short yl = f2bf(y - bf2f(yh));
        unsigned short zl = f2bf(z - bf2f(zh));
        unsigned short sh = f2bf(s), sl = f2bf(s - bf2f(sh));
        const unsigned short one = 0x3F80u;
        // -2 * bf16 is exact (power-of-two scale)
        unsigned short bxh = f2bf(-2.0f * bf2f(xh)), byh = f2bf(-2.0f * bf2f(yh)),
                       bzh = f2bf(-2.0f * bf2f(zh));
        unsigned short bxl = f2bf(-2.0f * bf2f(xl)), byl = f2bf(-2.0f * bf2f(yl)),
                       bzl = f2bf(-2.0f * bf2f(zl));
        unsigned short* A = afr + (size_t)idx * 16;
        A[0]=xh;  A[1]=yh;  A[2]=zh;   A[3]=xh;  A[4]=yh;  A[5]=zh;
        A[6]=xl;  A[7]=yl;  A[8]=zl;   A[9]=sh;  A[10]=sl; A[11]=one; A[12]=one;
        A[13]=xl; A[14]=yl; A[15]=zl;
        unsigned short* B = bfr + (size_t)idx * 16;
        B[0]=bxh; B[1]=byh; B[2]=bzh;  B[3]=bxl; B[4]=byl; B[5]=bzl;
        B[6]=bxh; B[7]=byh; B[8]=bzh;  B[9]=one; B[10]=one; B[11]=sh; B[12]=sl;
        B[13]=bxl; B[14]=byl; B[15]=bzl;
    }
}

// Kernel 2: R6 skeleton with QTILE = CHUNK = 1024 -> grid 1536 (6 blocks/CU
// available, ~5 co-resident) for latency coverage; single stage+barrier pair
// per block (same per-chunk barrier structure as R6). Low-VGPR 2-in-flight
// inner loop. Plain fminf only on MFMA outputs (NO inline asm). C/D
// placement self-calibrated by probe MFMA.
__global__ __launch_bounds__(BLK, 3)
void chamfer_kernel(const unsigned short* __restrict__ afr,
                    const unsigned short* __restrict__ bfr,
                    unsigned int* __restrict__ minbuf, int N) {
    __shared__ short8 sbuf[CHUNK * 2];            // 32 KB: [hi x1024][lo x1024]
    const int p  = blockIdx.z;
    const int pi = (p < 3) ? 0 : ((p < 5) ? 1 : 2);
    const int pj = (p < 3) ? (p + 1) : ((p < 5) ? (p - 1) : 3);
    const int tid  = threadIdx.x;
    const int w    = tid >> 6;
    const int l    = tid & 63;
    const int col  = l & 31;
    const int half = l >> 5;

    const int abase = (blockIdx.y * 4 + w) * 64;  // 64 a-rows per wave
    const int b0    = blockIdx.x * QTILE;

    const short8* aptr =
        (const short8*)(afr + ((size_t)pi * N + abase + col) * 16 + half * 8);
    const short8 A0 = aptr[0];
    const short8 A1 = aptr[64];                   // +32 points

    const char* gc = (const char*)(bfr + ((size_t)pj * N + b0) * 16);

    f32x16 m0, m1, zz;
#pragma unroll
    for (int i = 0; i < 16; ++i) { m0[i] = 3.402823466e38f; m1[i] = 3.402823466e38f; zz[i] = 0.0f; }

    // ---- stage the 1024-point chunk: 8 x 16B DMA per thread ----
#pragma unroll
    for (int it = 0; it < (CHUNK * 32) / (BLK * 16); ++it) {   // 8 iters
        int i = it * BLK + tid;               // 0..2047 linear LDS slot
        const char* src = (i < CHUNK) ? (gc + (size_t)i * 32)
                                      : (gc + (size_t)(i - CHUNK) * 32 + 16);
        __builtin_amdgcn_global_load_lds(
            (const __attribute__((address_space(1))) unsigned int*)src,
            (__attribute__((address_space(3))) unsigned int*)(sbuf + i),
            16, 0, 0);
    }
    __syncthreads();                          // drains vmcnt, data visible

    const short8* bsel = half ? (sbuf + CHUNK) : sbuf;
    for (int t = 0; t < CHUNK / 32; t += 2) { // 2 b-tiles per iteration
        short8 B0 = bsel[t * 32 + col];
        short8 B1 = bsel[(t + 1) * 32 + col];
        f32x16 d0 = __builtin_amdgcn_mfma_f32_32x32x16_bf16(A0, B0, zz, 0, 0, 0);
        f32x16 d1 = __builtin_amdgcn_mfma_f32_32x32x16_bf16(A0, B1, zz, 0, 0, 0);
#pragma unroll
        for (int i = 0; i < 16; ++i) m0[i] = fminf(m0[i], fminf(d0[i], d1[i]));
        d0 = __builtin_amdgcn_mfma_f32_32x32x16_bf16(A1, B0, zz, 0, 0, 0);
        d1 = __builtin_amdgcn_mfma_f32_32x32x16_bf16(A1, B1, zz, 0, 0, 0);
#pragma unroll
        for (int i = 0; i < 16; ++i) m1[i] = fminf(m1[i], fminf(d0[i], d1[i]));
    }

    // ---- layout probe: A[m][k]=m broadcast, B[k][n]=1 -> D[m][n]=16m ----
    short8 pa, po;
    unsigned short lv = f2bf((float)col);
#pragma unroll
    for (int i = 0; i < 8; ++i) { pa[i] = (short)lv; po[i] = (short)0x3F80u; }
    f32x16 pr = __builtin_amdgcn_mfma_f32_32x32x16_bf16(pa, po, zz, 0, 0, 0);
    int rowidx[16];
#pragma unroll
    for (int i = 0; i < 16; ++i) rowidx[i] = (int)(pr[i] * 0.0625f + 0.5f);
    const bool row_on_lane = (rowidx[0] == rowidx[1]);   // wave-uniform

    unsigned int* mb = minbuf + (size_t)p * N;
    if (!row_on_lane) {
        // cols on lanes: butterfly min across the 32 lanes of each half
#pragma unroll
        for (int off = 1; off <= 16; off <<= 1) {
#pragma unroll
            for (int i = 0; i < 16; ++i) {
                m0[i] = fminf(m0[i], __shfl_xor(m0[i], off, 64));
                m1[i] = fminf(m1[i], __shfl_xor(m1[i], off, 64));
            }
        }
        if (col == 0) {
#pragma unroll
            for (int r = 0; r < 16; ++r) {
                atomicMin(&mb[abase + rowidx[r]],
                          __float_as_uint(fmaxf(m0[r], 0.0f)));
                atomicMin(&mb[abase + 32 + rowidx[r]],
                          __float_as_uint(fmaxf(m1[r], 0.0f)));
            }
        }
    } else {
        // rows on lanes: min over regs in-lane, then across halves
        float v0 = m0[0], v1 = m1[0];
#pragma unroll
        for (int i = 1; i < 16; ++i) { v0 = fminf(v0, m0[i]); v1 = fminf(v1, m1[i]); }
        v0 = fminf(v0, __shfl_xor(v0, 32, 64));
        v1 = fminf(v1, __shfl_xor(v1, 32, 64));
        if (half == 0) {
            atomicMin(&mb[abase + col],      __float_as_uint(fmaxf(v0, 0.0f)));
            atomicMin(&mb[abase + 32 + col], __float_as_uint(fmaxf(v1, 0.0f)));
        }
    }
}

// Kernel 3: d = sqrt(min d^2), block-reduce, scaled atomicAdd into scalar out.
__global__ void finalize_kernel(const unsigned int* __restrict__ minbuf,
                                float* __restrict__ out, float scale) {
    __shared__ float red[BLK / 64];
    int idx = blockIdx.x * blockDim.x + threadIdx.x;
    float d = sqrtf(__uint_as_float(minbuf[idx]));
#pragma unroll
    for (int off = 32; off >= 1; off >>= 1)
        d += __shfl_down(d, off, 64);
    int lane = threadIdx.x & 63;
    int wid  = threadIdx.x >> 6;
    if (lane == 0) red[wid] = d;
    __syncthreads();
    if (threadIdx.x == 0) {
        float s = 0.0f;
#pragma unroll
        for (int wv = 0; wv < BLK / 64; ++wv) s += red[wv];
        atomicAdd(out, s * scale);
    }
}

extern "C" void kernel_launch(void* const* d_in, const int* in_sizes, int n_in,
                              void* d_out, int out_size, void* d_ws, size_t ws_size,
                              hipStream_t stream) {
    const float* points = (const float*)d_in[0];   // V x N x 3 fp32
    const float* poses  = (const float*)d_in[1];   // V x 4 x 4 fp32
    float* out = (float*)d_out;                    // scalar fp32

    const int N = in_sizes[0] / (VNUM * 3);        // 8192

    // ws: afr (V*N*16 bf16 = 1MB) | bfr (1MB) | minbuf (6*N uint = 192KB)
    unsigned short* afr = (unsigned short*)d_ws;
    unsigned short* bfr = afr + (size_t)VNUM * N * 16;
    unsigned int* minbuf = (unsigned int*)(bfr + (size_t)VNUM * N * 16);

    int setup_threads = NPAIRS * N;
    setup_kernel<<<(setup_threads + BLK - 1) / BLK, BLK, 0, stream>>>(
        points, poses, afr, bfr, minbuf, out, N);

    dim3 grid(N / QTILE, N / 256, NPAIRS);         // 8 x 32 x 6 = 1536 blocks
    chamfer_kernel<<<grid, BLK, 0, stream>>>(afr, bfr, minbuf, N);

    finalize_kernel<<<(NPAIRS * N) / BLK, BLK, 0, stream>>>(
        minbuf, out, 1.0f / (6.0f * (float)N));
}

// Round 12
// 31.932 us; speedup vs baseline: 1.1470x; 1.1470x over previous
//
#include <hip/hip_runtime.h>
#include <math.h>

// V=4 views, N=8192 points, 6 directed chamfer terms (pair p rows=view pi, min over view pj)
#define VNUM   4
#define NPAIRS 6
#define BLK    256
#define QTILE  2048   // b-points per block (quarter of N)
#define CHUNK  1024   // b-points staged per LDS phase (32 KB)

using short8  = __attribute__((ext_vector_type(8)))  short;
using f32x16  = __attribute__((ext_vector_type(16))) float;

__device__ inline unsigned short f2bf(float x) {           // RNE to bf16
    unsigned u = __float_as_uint(x);
    return (unsigned short)((u + 0x7FFFu + ((u >> 16) & 1u)) >> 16);
}
__device__ inline float bf2f(unsigned short b) {
    return __uint_as_float(((unsigned)b) << 16);
}
__device__ inline unsigned pk(unsigned short lo, unsigned short hi) {
    return (unsigned)lo | ((unsigned)hi << 16);
}

// Kernel 1: world-transform, build K=16 bf16 fragments so that
// dot(Afrag[a], Bfrag[b]) = |a|^2 + |b|^2 - 2*(a_hi+a_lo).(b_hi+b_lo).
// Fragment stores vectorized to 2 x uint4 per array.
__global__ void setup_kernel(const float* __restrict__ pts,
                             const float* __restrict__ poses,
                             unsigned short* __restrict__ afr,
                             unsigned short* __restrict__ bfr,
                             unsigned int* __restrict__ minbuf,
                             float* __restrict__ out, int N) {
    int idx = blockIdx.x * blockDim.x + threadIdx.x;
    if (idx < NPAIRS * N) minbuf[idx] = 0x7F7FFFFFu;       // FLT_MAX bits
    if (idx == 0) *out = 0.0f;
    if (idx < VNUM * N) {
        int v = idx / N;
        const float* P = poses + v * 16;                   // row-major 4x4
        float px = pts[idx*3+0], py = pts[idx*3+1], pz = pts[idx*3+2];
        float x = fmaf(P[0], px, fmaf(P[1], py, fmaf(P[2],  pz, P[3])));
        float y = fmaf(P[4], px, fmaf(P[5], py, fmaf(P[6],  pz, P[7])));
        float z = fmaf(P[8], px, fmaf(P[9], py, fmaf(P[10], pz, P[11])));
        float s = fmaf(x, x, fmaf(y, y, z * z));
        unsigned short xh = f2bf(x), yh = f2bf(y), zh = f2bf(z);
        unsigned short xl = f2bf(x - bf2f(xh));
        unsigned short yl = f2bf(y - bf2f(yh));
        unsigned short zl = f2bf(z - bf2f(zh));
        unsigned short sh = f2bf(s), sl = f2bf(s - bf2f(sh));
        const unsigned short one = 0x3F80u;
        // -2 * bf16 is exact (power-of-two scale)
        unsigned short bxh = f2bf(-2.0f * bf2f(xh)), byh = f2bf(-2.0f * bf2f(yh)),
                       bzh = f2bf(-2.0f * bf2f(zh));
        unsigned short bxl = f2bf(-2.0f * bf2f(xl)), byl = f2bf(-2.0f * bf2f(yl)),
                       bzl = f2bf(-2.0f * bf2f(zl));
        // A[0..15] = xh,yh,zh, xh,yh,zh, xl,yl,zl, sh,sl, one,one, xl,yl,zl
        uint4* A4 = (uint4*)(afr + (size_t)idx * 16);
        A4[0] = make_uint4(pk(xh,yh), pk(zh,xh), pk(yh,zh), pk(xl,yl));
        A4[1] = make_uint4(pk(zl,sh), pk(sl,one), pk(one,xl), pk(yl,zl));
        // B[0..15] = bxh,byh,bzh, bxl,byl,bzl, bxh,byh,bzh, one,one, sh,sl, bxl,byl,bzl
        uint4* B4 = (uint4*)(bfr + (size_t)idx * 16);
        B4[0] = make_uint4(pk(bxh,byh), pk(bzh,bxl), pk(byl,bzl), pk(bxh,byh));
        B4[1] = make_uint4(pk(bzh,one), pk(one,sh), pk(sl,bxl), pk(byl,bzl));
    }
}

// Kernel 2: R6 skeleton. Hard-coded HW-verified C/D mapping for
// mfma_f32_32x32x16_bf16: col = lane&31, row = (reg&3) + 8*(reg>>2) +
// 4*(lane>>5)  [learn_hip m74/m101, end-to-end verified]. No probe MFMA.
// Plain fminf only on MFMA outputs (NO inline asm). s_setprio(1) around
// the MFMA cluster (T5).
__global__ __launch_bounds__(BLK, 3)
void chamfer_kernel(const unsigned short* __restrict__ afr,
                    const unsigned short* __restrict__ bfr,
                    unsigned int* __restrict__ minbuf, int N) {
    __shared__ short8 sbuf[CHUNK * 2];            // 32 KB: [hi x1024][lo x1024]
    const int p  = blockIdx.z;
    const int pi = (p < 3) ? 0 : ((p < 5) ? 1 : 2);
    const int pj = (p < 3) ? (p + 1) : ((p < 5) ? (p - 1) : 3);
    const int tid  = threadIdx.x;
    const int w    = tid >> 6;
    const int l    = tid & 63;
    const int col  = l & 31;
    const int half = l >> 5;

    const int abase = (blockIdx.y * 4 + w) * 64;  // 64 a-rows per wave
    const int b0    = blockIdx.x * QTILE;

    const short8* aptr =
        (const short8*)(afr + ((size_t)pi * N + abase + col) * 16 + half * 8);
    const short8 A0 = aptr[0];
    const short8 A1 = aptr[64];                   // +32 points

    const char* gq = (const char*)(bfr + ((size_t)pj * N + b0) * 16);

    f32x16 m0, m1, zz;
#pragma unroll
    for (int i = 0; i < 16; ++i) { m0[i] = 3.402823466e38f; m1[i] = 3.402823466e38f; zz[i] = 0.0f; }

    for (int c = 0; c < QTILE / CHUNK; ++c) {
        __syncthreads();                          // previous phase fully consumed
        const char* gc = gq + (size_t)c * CHUNK * 32;
#pragma unroll
        for (int it = 0; it < (CHUNK * 32) / (BLK * 16); ++it) {   // 8 iters
            int i = it * BLK + tid;               // 0..2047 linear LDS slot
            const char* src = (i < CHUNK) ? (gc + (size_t)i * 32)
                                          : (gc + (size_t)(i - CHUNK) * 32 + 16);
            __builtin_amdgcn_global_load_lds(
                (const __attribute__((address_space(1))) unsigned int*)src,
                (__attribute__((address_space(3))) unsigned int*)(sbuf + i),
                16, 0, 0);
        }
        __syncthreads();                          // drains vmcnt, data visible

        const short8* bsel = half ? (sbuf + CHUNK) : sbuf;
        for (int t = 0; t < CHUNK / 32; t += 2) { // 2 b-tiles per iteration
            short8 B0 = bsel[t * 32 + col];
            short8 B1 = bsel[(t + 1) * 32 + col];
            __builtin_amdgcn_s_setprio(1);
            f32x16 d00 = __builtin_amdgcn_mfma_f32_32x32x16_bf16(A0, B0, zz, 0, 0, 0);
            f32x16 d01 = __builtin_amdgcn_mfma_f32_32x32x16_bf16(A0, B1, zz, 0, 0, 0);
            f32x16 d10 = __builtin_amdgcn_mfma_f32_32x32x16_bf16(A1, B0, zz, 0, 0, 0);
            f32x16 d11 = __builtin_amdgcn_mfma_f32_32x32x16_bf16(A1, B1, zz, 0, 0, 0);
            __builtin_amdgcn_s_setprio(0);
#pragma unroll
            for (int i = 0; i < 16; ++i) {        // fminf only -> v_min3 fusion
                m0[i] = fminf(m0[i], fminf(d00[i], d01[i]));
                m1[i] = fminf(m1[i], fminf(d10[i], d11[i]));
            }
        }
    }

    // ---- epilogue: butterfly min across the 32 lanes of each half ----
#pragma unroll
    for (int off = 1; off <= 16; off <<= 1) {
#pragma unroll
        for (int i = 0; i < 16; ++i) {
            m0[i] = fminf(m0[i], __shfl_xor(m0[i], off, 64));
            m1[i] = fminf(m1[i], __shfl_xor(m1[i], off, 64));
        }
    }
    if (col == 0) {
        unsigned int* mb = minbuf + (size_t)p * N;
#pragma unroll
        for (int r = 0; r < 16; ++r) {
            int row = (r & 3) + 8 * (r >> 2) + 4 * half;   // verified C/D mapping
            atomicMin(&mb[abase + row],
                      __float_as_uint(fmaxf(m0[r], 0.0f)));
            atomicMin(&mb[abase + 32 + row],
                      __float_as_uint(fmaxf(m1[r], 0.0f)));
        }
    }
}

// Kernel 3: d = sqrt(min d^2), block-reduce, scaled atomicAdd into scalar out.
__global__ void finalize_kernel(const unsigned int* __restrict__ minbuf,
                                float* __restrict__ out, float scale) {
    __shared__ float red[BLK / 64];
    int idx = blockIdx.x * blockDim.x + threadIdx.x;
    float d = sqrtf(__uint_as_float(minbuf[idx]));
#pragma unroll
    for (int off = 32; off >= 1; off >>= 1)
        d += __shfl_down(d, off, 64);
    int lane = threadIdx.x & 63;
    int wid  = threadIdx.x >> 6;
    if (lane == 0) red[wid] = d;
    __syncthreads();
    if (threadIdx.x == 0) {
        float s = 0.0f;
#pragma unroll
        for (int wv = 0; wv < BLK / 64; ++wv) s += red[wv];
        atomicAdd(out, s * scale);
    }
}

extern "C" void kernel_launch(void* const* d_in, const int* in_sizes, int n_in,
                              void* d_out, int out_size, void* d_ws, size_t ws_size,
                              hipStream_t stream) {
    const float* points = (const float*)d_in[0];   // V x N x 3 fp32
    const float* poses  = (const float*)d_in[1];   // V x 4 x 4 fp32
    float* out = (float*)d_out;                    // scalar fp32

    const int N = in_sizes[0] / (VNUM * 3);        // 8192

    // ws: afr (V*N*16 bf16 = 1MB) | bfr (1MB) | minbuf (6*N uint = 192KB)
    unsigned short* afr = (unsigned short*)d_ws;
    unsigned short* bfr = afr + (size_t)VNUM * N * 16;
    unsigned int* minbuf = (unsigned int*)(bfr + (size_t)VNUM * N * 16);

    int setup_threads = NPAIRS * N;
    setup_kernel<<<(setup_threads + BLK - 1) / BLK, BLK, 0, stream>>>(
        points, poses, afr, bfr, minbuf, out, N);

    dim3 grid(N / QTILE, N / 256, NPAIRS);         // 4 x 32 x 6 = 768 blocks
    chamfer_kernel<<<grid, BLK, 0, stream>>>(afr, bfr, minbuf, N);

    finalize_kernel<<<(NPAIRS * N) / BLK, BLK, 0, stream>>>(
        minbuf, out, 1.0f / (6.0f * (float)N));
}